// Round 5
// baseline (116.304 us; speedup 1.0000x reference)
//
#include <hip/hip_runtime.h>
#include <hip/hip_bf16.h>
#include <math.h>

typedef __attribute__((ext_vector_type(8))) short bf16x8;
typedef __attribute__((ext_vector_type(4))) float f32x4;

#define NSAMP  128000
#define TFR    501
#define NFR    32064       // 64*501 frames per signal
#define FPOW   257
#define NF     257
#define B_SZ   64
#define CHUNKT 32
#define NCH    16
#define EPS_F  1.1920928955078125e-07f

#define SEG    33024       // 128*256 + 256 samples per M-chunk segment
#define SEGB   66048       // SEG * 2 bytes (bf16)
#define BBUFB  32768       // 256 cols * 128 B per K-step tile
#define LDS_TOTAL (SEGB + 2 * BBUFB)   // 131584 B

// ---- basis, layout [st 0..7][col 0..511][k 0..63] bf16 -----------------
// col = (bin>>4)*32 + isIm*16 + (bin&15); col 16 (dead im of DC) = Nyquist.
__global__ __launch_bounds__(256)
void build_basis(unsigned short* __restrict__ Bt) {
    int col = blockIdx.x;
    int g = col >> 5, o = col & 15;
    int isIm = (col >> 4) & 1;
    int bin = g * 16 + o;
    for (int k = threadIdx.x; k < 512; k += 256) {
        float w = sinf((float)k * (float)(M_PI / 512.0));   // sqrt-hann
        float v;
        if (col == 16) {
            v = w * ((k & 1) ? -1.f : 1.f);
        } else {
            int mm = (bin * k) & 511;
            float th = (float)mm * (float)(2.0 * M_PI / 512.0);
            v = w * (isIm ? -sinf(th) : cosf(th));
        }
        __hip_bfloat16 h = __float2bfloat16(v);
        Bt[((size_t)(k >> 6) * 512 + col) * 64 + (k & 63)] =
            *reinterpret_cast<unsigned short*>(&h);
    }
}

// ---- MFMA DFT GEMM v5: r3 layout + m201-style phase schedule ------------
__global__ __launch_bounds__(512, 2)
void dft_gemm(const float* __restrict__ sig,
              const float* __restrict__ intf,
              const unsigned short* __restrict__ Bt,
              float* __restrict__ powo)
{
    extern __shared__ char smem[];
    char* As = smem;

    const int mchunk = blockIdx.x, b = blockIdx.y, s = blockIdx.z;
    const int tid = threadIdx.x, lane = tid & 63, wid = tid >> 6;
    const int wm = wid >> 2, wn = wid & 3;
    const float* x = (s == 0 ? intf : sig) + (size_t)b * NSAMP;
    const int tbase = mchunk * 32768 - 256;

    const int colSub = lane >> 3;
    const int bchunk = (lane & 7) ^ colSub;
    auto stageB = [&](int q, int buf) {
        const int nt = q >> 3, st = q & 7;
        const char* gb = (const char*)Bt + ((size_t)(st * 512 + nt * 256)) * 128;
        char* lb = smem + SEGB + buf * BBUFB;
        #pragma unroll
        for (int i = 0; i < 4; ++i) {
            const char* src = gb + (size_t)(wid * 32 + i * 8 + colSub) * 128
                                 + bchunk * 16;
            char* dst = lb + (wid * 32 + i * 8) * 128;
            __builtin_amdgcn_global_load_lds(
                (const __attribute__((address_space(1))) void*)src,
                (__attribute__((address_space(3))) void*)dst, 16, 0, 0);
        }
    };

    stageB(0, 0);

    // ---- A staging: contiguous segment, float4, bf16, addr-XOR swizzle ----
    {
        const int jlo = (tbase < 0) ? -tbase : 0;
        const int jhi = (tbase + SEG > NSAMP) ? (NSAMP - tbase) : SEG;
        for (int i = tid; i < SEG / 4; i += 512) {
            int j = i * 4;
            float f0, f1, f2, f3;
            if (j >= jlo && j + 4 <= jhi) {
                float4 v = *(const float4*)(x + tbase + j);
                f0 = v.x; f1 = v.y; f2 = v.z; f3 = v.w;
            } else {
                int p0 = tbase + j;
                int pp[4];
                #pragma unroll
                for (int e = 0; e < 4; ++e) {
                    int p = p0 + e;
                    if (p < 0) p = -p;
                    if (p >= NSAMP) p = 2 * NSAMP - 2 - p;
                    pp[e] = p;
                }
                f0 = x[pp[0]]; f1 = x[pp[1]]; f2 = x[pp[2]]; f3 = x[pp[3]];
            }
            unsigned short h[4];
            __hip_bfloat16 t0 = __float2bfloat16(f0); h[0] = *(unsigned short*)&t0;
            __hip_bfloat16 t1 = __float2bfloat16(f1); h[1] = *(unsigned short*)&t1;
            __hip_bfloat16 t2 = __float2bfloat16(f2); h[2] = *(unsigned short*)&t2;
            __hip_bfloat16 t3 = __float2bfloat16(f3); h[3] = *(unsigned short*)&t3;
            unsigned long long pk =
                (unsigned long long)h[0] | ((unsigned long long)h[1] << 16) |
                ((unsigned long long)h[2] << 32) | ((unsigned long long)h[3] << 48);
            int a = i * 8;
            a ^= ((a >> 9) & 7) << 4;
            *(unsigned long long*)(As + a) = pk;
        }
    }
    asm volatile("s_waitcnt vmcnt(0)" ::: "memory");
    __syncthreads();

    f32x4 acc[4][4];
    #pragma unroll
    for (int i = 0; i < 4; ++i)
        #pragma unroll
        for (int j = 0; j < 4; ++j) acc[i][j] = 0;

    const size_t rowbase = ((size_t)(s * 64 + b)) * TFR;
    const int olane = lane & 15, qlane = lane >> 4;

    for (int q = 0; q < 16; ++q) {
        const char* bufp = smem + SEGB + (q & 1) * BBUFB;
        const int st = q & 7;

        #pragma unroll
        for (int kb = 0; kb < 2; ++kb) {
            const int ko = kb * 64 + (lane >> 4) * 16;
            bf16x8 af[4], bfr[4];
            // ---- phase front: ds_read this sub-tile's fragments ----
            #pragma unroll
            for (int mf = 0; mf < 4; ++mf) {
                int row = wm * 64 + mf * 16 + (lane & 15);
                int a = row * 512 + st * 128 + ko;
                a ^= ((a >> 9) & 7) << 4;
                af[mf] = *(const bf16x8*)(As + a);
            }
            #pragma unroll
            for (int nf = 0; nf < 4; ++nf) {
                int col = wn * 64 + nf * 16 + (lane & 15);
                int bo = col * 128 + ko;
                bo ^= ((bo >> 7) & 7) << 4;
                bfr[nf] = *(const bf16x8*)(bufp + bo);
            }
            // issue next-tile global->LDS in phase 0 (lands before q-end drain)
            if (kb == 0 && q < 15) stageB(q + 1, (q + 1) & 1);

            __builtin_amdgcn_s_barrier();
            asm volatile("s_waitcnt lgkmcnt(0)" ::: "memory");
            __builtin_amdgcn_sched_barrier(0);
            __builtin_amdgcn_s_setprio(1);
            #pragma unroll
            for (int mf = 0; mf < 4; ++mf)
                #pragma unroll
                for (int nf = 0; nf < 4; ++nf)
                    acc[mf][nf] = __builtin_amdgcn_mfma_f32_16x16x32_bf16(
                        af[mf], bfr[nf], acc[mf][nf], 0, 0, 0);
            __builtin_amdgcn_s_setprio(0);
            __builtin_amdgcn_sched_barrier(0);
            if (kb == 1)   // drain own 4 stage loads (issued ~1 phase ago)
                asm volatile("s_waitcnt vmcnt(0)" ::: "memory");
            __builtin_amdgcn_s_barrier();
        }

        if (st == 7) {
            const int nt = q >> 3;
            #pragma unroll
            for (int mf = 0; mf < 4; ++mf) {
                #pragma unroll
                for (int p = 0; p < 2; ++p) {
                    f32x4 re = acc[mf][2 * p], im = acc[mf][2 * p + 1];
                    int g2 = nt * 8 + wn * 2 + p;
                    int bin = g2 * 16 + olane;
                    bool nyq = (g2 == 0) && (olane == 0);
                    #pragma unroll
                    for (int j = 0; j < 4; ++j) {
                        int rl = mchunk * 128 + wm * 64 + mf * 16 + qlane * 4 + j;
                        if (rl < TFR) {
                            float pr = re[j] * re[j];
                            float pi = im[j] * im[j];
                            float* po = powo + (rowbase + rl) * FPOW;
                            po[bin] = nyq ? pr : (pr + pi);
                            if (nyq) po[256] = pi;
                        }
                    }
                }
            }
            #pragma unroll
            for (int i = 0; i < 4; ++i)
                #pragma unroll
                for (int j = 0; j < 4; ++j) acc[i][j] = 0;
        }
    }
}

// ---- warm-up: batched loads then fmaf chain -----------------------------
template<int W>
__device__ __forceinline__ float warm_sum(const float* __restrict__ nrow,
                                          int ts, float alpha, float oma) {
    float q[W + 1];
    #pragma unroll
    for (int i = 0; i <= W; ++i) q[i] = nrow[(size_t)(ts + i) * FPOW];
    float v = q[0];
    #pragma unroll
    for (int i = 1; i <= W; ++i) v = fmaf(alpha, v, oma * q[i]);
    return v;
}

// ---- chunked IIR scan + SPP + MSE, pipelined & unrolled ----------------
__global__ __launch_bounds__(256, 4)
void spp_loss_kernel(const float* __restrict__ noiseP,
                     const float* __restrict__ noisyP,
                     const float* __restrict__ est,
                     float* __restrict__ out,
                     float alpha)
{
    const double XI = 31.622776601683793;
    const float RATIO = (float)(1.0 + XI);
    const float COEF  = (float)(XI / (1.0 + XI));
    const float INVN  = (float)(1.0 / ((double)B_SZ * NF * TFR));

    int tid = blockIdx.x * blockDim.x + threadIdx.x;
    int f   = tid % NF;
    int rem = tid / NF;
    int c   = rem & (NCH - 1);
    int b   = rem >> 4;

    float local = 0.f;
    if (b < B_SZ) {
        const int t0   = c * CHUNKT;
        const int tend = min(TFR, t0 + CHUNKT);
        const float* nrow = noiseP + (size_t)b * TFR * FPOW + f;
        const float* yrow = noisyP + (size_t)b * TFR * FPOW + f;
        const float* erow = est + ((size_t)b * NF + f) * TFR;
        const float oma = 1.f - alpha;

        float v;
        if (t0 == 0)            v = nrow[0];
        else if (t0 == CHUNKT)  v = warm_sum<CHUNKT>(nrow, 0, alpha, oma);
        else                    v = warm_sum<48>(nrow, t0 - 48, alpha, oma);

        {
            float np = yrow[(size_t)t0 * FPOW];
            float e0 = erow[t0];
            float expo = -np / (v + EPS_F) * COEF;
            float spp  = 1.f / fmaf(RATIO, __expf(expo), 1.f);
            float d = e0 - spp;
            local = fmaf(d, d, local);
        }
        #pragma unroll
        for (int h = 0; h < 2; ++h) {
            float qn[16], qy[16], qe[16];
            #pragma unroll
            for (int i = 0; i < 16; ++i) {
                int t = min(t0 + h * 16 + i + 1, TFR - 1);
                qn[i] = nrow[(size_t)t * FPOW];
                qy[i] = yrow[(size_t)t * FPOW];
                qe[i] = erow[t];
            }
            #pragma unroll
            for (int i = 0; i < 16; ++i) {
                int t = t0 + h * 16 + i + 1;
                v = fmaf(alpha, v, oma * qn[i]);
                if (t < tend) {
                    float expo = -qy[i] / (v + EPS_F) * COEF;
                    float spp  = 1.f / fmaf(RATIO, __expf(expo), 1.f);
                    float d = qe[i] - spp;
                    local = fmaf(d, d, local);
                }
            }
        }
    }

    for (int off = 32; off > 0; off >>= 1)
        local += __shfl_down(local, off);
    __shared__ float wsum[4];
    if ((threadIdx.x & 63) == 0) wsum[threadIdx.x >> 6] = local;
    __syncthreads();
    if (threadIdx.x == 0) {
        float ssum = (wsum[0] + wsum[1]) + (wsum[2] + wsum[3]);
        atomicAdd(out, ssum * INVN);
    }
}

extern "C" void kernel_launch(void* const* d_in, const int* in_sizes, int n_in,
                              void* d_out, int out_size, void* d_ws, size_t ws_size,
                              hipStream_t stream) {
    const float* est  = (const float*)d_in[0];   // spp_estimate (B,1,F,T)
    const float* sig  = (const float*)d_in[1];   // input_sig    (B,1,N)
    const float* intf = (const float*)d_in[2];   // interference (B,1,N)

    unsigned short* Bt = (unsigned short*)d_ws;                 // 512 KB basis
    float* powp = (float*)((char*)d_ws + (size_t)8 * 512 * 64 * 2);

    hipLaunchKernelGGL(build_basis, dim3(512), dim3(256), 0, stream, Bt);
    hipMemsetAsync(d_out, 0, sizeof(float), stream);

    hipFuncSetAttribute((const void*)dft_gemm,
                        hipFuncAttributeMaxDynamicSharedMemorySize, LDS_TOTAL);
    dim3 gG(4, 64, 2);
    hipLaunchKernelGGL(dft_gemm, gG, dim3(512), LDS_TOTAL, stream,
                       sig, intf, Bt, powp);

    const double alpha_d = exp(-((double)256) / (16000.0 * 0.072));
    const float* noiseP = powp;                          // s=0: interference
    const float* noisyP = powp + (size_t)NFR * FPOW;     // s=1: input_sig
    dim3 gB((B_SZ * NCH * NF + 255) / 256);
    hipLaunchKernelGGL(spp_loss_kernel, gB, dim3(256), 0, stream,
                       noiseP, noisyP, est, (float*)d_out, (float)alpha_d);
}